// Round 4
// baseline (141.216 us; speedup 1.0000x reference)
//
#include <hip/hip_runtime.h>
#include <hip/hip_bf16.h>

// BasicBlock (ReActNet-style) fused pipeline, MI355X gfx950.
// I/O dtype: FLOAT32. conv3x3 & conv1x1 as exact-integer bf16 MFMA GEMMs.
// R4: depth-4 counted-vmcnt pipeline (T3+T4): STAGE(k+3) -> vmcnt(9) -> bar ->
//     MFMA(k) -> bar. Loads stay in flight across 3 iterations (never drain to 0
//     in the main loop). 64px x 128ch tile, 4 waves, BK=32.

typedef unsigned short u16;
typedef __bf16 bf16x8 __attribute__((ext_vector_type(8)));
typedef float  f32x4  __attribute__((ext_vector_type(4)));

#define GLD16(gsrc, ldst) \
  __builtin_amdgcn_global_load_lds((__attribute__((address_space(1))) void*)(gsrc), \
                                   (__attribute__((address_space(3))) void*)(ldst), 16, 0, 0)

__device__ __forceinline__ float b2f(u16 u) {
  union { unsigned int i; float f; } c; c.i = ((unsigned int)u) << 16; return c.f;
}
__device__ __forceinline__ u16 f2b(float f) {
  unsigned int u = __builtin_bit_cast(unsigned int, f);
  unsigned int r = (u + 0x7FFFu + ((u >> 16) & 1u)) >> 16;   // RNE
  return (u16)r;
}
__device__ __forceinline__ float sgnf(float v) {
  return (v > 0.f) ? 1.f : ((v < 0.f) ? -1.f : 0.f);
}

// ---------------- prep: binarize weights (transposed [o][k]), fold scale*BN, zero page, loss ----
__global__ __launch_bounds__(256) void prep_kernel(
    const float* __restrict__ w1, const float* __restrict__ w2,
    const float* __restrict__ g1, const float* __restrict__ be1,
    const float* __restrict__ m1, const float* __restrict__ v1,
    const float* __restrict__ g2, const float* __restrict__ be2,
    const float* __restrict__ m2, const float* __restrict__ v2,
    u16* __restrict__ wsgn1, u16* __restrict__ wsgn2,
    float* __restrict__ ab, float* __restrict__ zp,
    float* __restrict__ lossdst, const float* __restrict__ lossin)
{
  __shared__ float red[256];
  const int t = threadIdx.x;
  const int blk = blockIdx.x;
  float s = 0.f;
  if (blk < 256) {                       // w1: [o][i][3][3] -> wsgn1[o][(kh*3+kw)*256 + i]
    const int o = blk;
    for (int jj = t; jj < 2304; jj += 256) {
      float v = w1[o * 2304 + jj];
      s += fabsf(v);
      int i = jj / 9, sh = jj % 9;
      wsgn1[o * 2304 + sh * 256 + i] = f2b(sgnf(v));
    }
  } else {                               // w2: [o][i] -> wsgn2[o][i]
    const int o = blk - 256;
    float v = w2[o * 256 + t];
    s = fabsf(v);
    wsgn2[o * 256 + t] = f2b(sgnf(v));
  }
  red[t] = s;
  __syncthreads();
  for (int st = 128; st > 0; st >>= 1) { if (t < st) red[t] += red[t + st]; __syncthreads(); }
  if (t == 0) {
    if (blk < 256) {
      const int o = blk;
      float scale = red[0] / 2304.f;
      float inv = g1[o] / sqrtf(v1[o] + 1e-5f);
      ab[o]       = scale * inv;                 // alpha1
      ab[256 + o] = be1[o] - m1[o] * inv;        // beta1
    } else {
      const int o = blk - 256;
      float scale = red[0] / 256.f;
      float inv = g2[o] / sqrtf(v2[o] + 1e-5f);
      ab[512 + o] = scale * inv;                 // alpha2
      ab[768 + o] = be2[o] - m2[o] * inv;        // beta2
    }
  }
  if (blk == 0 && t < 64) zp[t] = 0.f;           // 256B zero page (conv padding gather)
  if (blk == 0 && t == 0) lossdst[0] = lossin[0];// loss passthrough (f32)
}

// ---------------- act1 = sign(x + b11), NCHW f32 -> NHWC bf16 transpose via LDS ----------------
__global__ __launch_bounds__(256) void act1_kernel(
    const float* __restrict__ x, const float* __restrict__ b11, u16* __restrict__ act1)
{
  __shared__ u16 lds[112 * 68];
  const int t = threadIdx.x;
  const int p0 = blockIdx.x * 112;     // 7 tiles * 112 = 784 pixels
  const int c0 = blockIdx.y * 64;      // 4 tiles * 64 = 256 ch
  const int b  = blockIdx.z;
  const float* xb = x + (size_t)b * 200704;
#pragma unroll
  for (int it = 0; it < 7; ++it) {     // read x coalesced (float4), sign, store LDS[p][c]
    int flat = it * 256 + t;           // (c:64, p4:28)
    int c = flat / 28;
    int p = (flat % 28) * 4;
    float4 v4 = *(const float4*)(xb + (size_t)(c0 + c) * 784 + p0 + p);
    float bb = b11[c0 + c];
    lds[(p + 0) * 68 + c] = f2b(sgnf(v4.x + bb));
    lds[(p + 1) * 68 + c] = f2b(sgnf(v4.y + bb));
    lds[(p + 2) * 68 + c] = f2b(sgnf(v4.z + bb));
    lds[(p + 3) * 68 + c] = f2b(sgnf(v4.w + bb));
  }
  __syncthreads();
#pragma unroll
  for (int it = 0; it < 7; ++it) {     // write act1 NHWC coalesced (ushort4)
    int flat = it * 256 + t;           // (p:112, c4:16)
    int p = flat / 16;
    int c = (flat % 16) * 4;
    ushort4 v4 = *(const ushort4*)(&lds[p * 68 + c]);
    *(ushort4*)(act1 + ((size_t)(b * 784 + p0 + p)) * 256 + c0 + c) = v4;
  }
}

// ---------------- GEMM (MODE 0: conv3x3 K=2304 ; MODE 1: conv1x1 K=256) ----------------
// Block tile 64px x 128ch, 4 waves (each 32x64), 16x16x32 bf16 MFMA, BK=32.
// Depth-4 counted-vmcnt pipeline: 3 K-steps of loads always in flight.
template<int MODE>
__global__ __launch_bounds__(256, 3) void gemm_kernel(
    const u16* __restrict__ act,       // NHWC bf16 [25088][256]
    const u16* __restrict__ wsgn,      // [256][KSTR] bf16 signs
    const float* __restrict__ alphav,
    const float* __restrict__ betav,
    const float* __restrict__ biasA,   // b12 / b22
    const float* __restrict__ slope,   // a1  / a2
    const float* __restrict__ biasB,   // b13 / b23
    const float* __restrict__ b21,     // MODE0 only
    const float* __restrict__ x,       // MODE0 only: NCHW f32 residual
    u16* __restrict__ out1b,           // MODE0: write bf16 ; MODE1: read (residual)
    u16* __restrict__ act2,            // MODE0: write sign(out1+b21) NHWC
    float* __restrict__ dout,          // MODE1: write NCHW f32
    const float* __restrict__ zp)
{
  constexpr int KSTEPS = (MODE == 0) ? 72 : 8;
  constexpr int KSTR   = (MODE == 0) ? 2304 : 256;

  __shared__ __align__(16) u16 ldsA[4][64 * 32];    // 4 x 4 KiB
  __shared__ __align__(16) u16 ldsB[4][128 * 32];   // 4 x 8 KiB

  const int t = threadIdx.x;
  const int w = t >> 6;
  const int l = t & 63;
  const int blkPx = blockIdx.x * 64;
  const int blkCh = blockIdx.y * 128;

  // staging geometry: wave w stages A rows [w*16,w*16+16), B chunks w and w+4
  const int rc   = l >> 2;
  const int swzB = (((l & 3) ^ ((rc >> 1) & 3)) << 4);  // XOR chunk swizzle (2-way banks = free)
  const int aPix = blkPx + w * 16 + rc;
  const int hw0  = aPix % 784;
  const int aH   = hw0 / 28, aW = hw0 % 28;
  const int bRow0 = blkCh + w * 16 + rc;
  const int bRow1 = blkCh + 64 + w * 16 + rc;

  // fragment read byte offsets (constant across K)
  const int pxBase = (w & 1) * 32;
  const int chBase = (w >> 1) * 64;
  int aoff[2], boff[4];
#pragma unroll
  for (int i = 0; i < 2; ++i) {
    int ra = pxBase + i * 16 + (l & 15);
    aoff[i] = ra * 64 + (((l >> 4) ^ ((ra >> 1) & 3)) << 4);
  }
#pragma unroll
  for (int i = 0; i < 4; ++i) {
    int rb = chBase + i * 16 + (l & 15);
    boff[i] = rb * 64 + (((l >> 4) ^ ((rb >> 1) & 3)) << 4);
  }

  // ---- epilogue params loaded BEFORE the pipeline (keeps vmcnt FIFO clean in-loop) ----
  const int lane16 = l & 15;
  const int laneQ  = l >> 4;
  float al[4], bt[4], pA[4], pS[4], pB[4], p21[4];
#pragma unroll
  for (int ni = 0; ni < 4; ++ni) {
    int o = blkCh + chBase + ni * 16 + lane16;
    al[ni] = alphav[o];
    bt[ni] = betav[o];
    pA[ni] = biasA[o];
    pS[ni] = slope[o];
    pB[ni] = biasB[o];
    p21[ni] = (MODE == 0) ? b21[o] : 0.f;
  }
  asm volatile("" ::: "memory");   // params issued before any STAGE

  f32x4 acc[2][4];
  f32x4 zero4 = {0.f, 0.f, 0.f, 0.f};
#pragma unroll
  for (int i = 0; i < 2; ++i)
#pragma unroll
    for (int j = 0; j < 4; ++j) acc[i][j] = zero4;

  const char* actc = (const char*)act;
  const char* wsc  = (const char*)wsgn;
  const char* zpc  = (const char*)zp;
  char* A0 = (char*)&ldsA[0][0];
  char* B0 = (char*)&ldsB[0][0];

  auto STAGE = [&](int buf, int kk) {    // 3 GLD16 per thread, ALWAYS (uniform vmcnt count)
    char* dA = A0 + buf * 4096;
    char* dB = B0 + buf * 8192;
    if (MODE == 0) {
      int shift = kk >> 3;
      int d3 = (shift * 11) >> 5;        // shift/3 for 0..8
      int dh = d3 - 1, dw = shift - 3 * d3 - 1;
      int kb = (kk & 7) * 64;
      bool ok = ((unsigned)(aH + dh) < 28u) & ((unsigned)(aW + dw) < 28u);
      const char* srcA = ok ? actc + (size_t)(aPix + dh * 28 + dw) * 512 + kb + swzB
                            : zpc + swzB;
      GLD16(srcA, dA + w * 1024 + l * 16);
    } else {
      GLD16(actc + (size_t)aPix * 512 + kk * 64 + swzB, dA + w * 1024 + l * 16);
    }
    GLD16(wsc + (size_t)bRow0 * (KSTR * 2) + kk * 64 + swzB, dB + w * 1024 + l * 16);
    GLD16(wsc + (size_t)bRow1 * (KSTR * 2) + kk * 64 + swzB, dB + (w + 4) * 1024 + l * 16);
  };

  auto COMPUTE = [&](int buf) {
    const char* sA = A0 + buf * 4096;
    const char* sB = B0 + buf * 8192;
    bf16x8 af[2], bfr[4];
#pragma unroll
    for (int i = 0; i < 2; ++i) af[i]  = *(const bf16x8*)(sA + aoff[i]);
#pragma unroll
    for (int i = 0; i < 4; ++i) bfr[i] = *(const bf16x8*)(sB + boff[i]);
#pragma unroll
    for (int mi = 0; mi < 2; ++mi)
#pragma unroll
      for (int ni = 0; ni < 4; ++ni)
        acc[mi][ni] = __builtin_amdgcn_mfma_f32_16x16x32_bf16(af[mi], bfr[ni], acc[mi][ni], 0, 0, 0);
  };

  // ---- prologue: stage steps 0,1,2 (9 loads in flight) ----
  STAGE(0, 0); STAGE(1, 1); STAGE(2, 2);

  // ---- main loop: stage k+3, wait only for step k (vmcnt 9 = 3 newer steps in flight) ----
#pragma unroll 1
  for (int k = 0; k < KSTEPS - 3; ++k) {
    STAGE((k + 3) & 3, k + 3);           // overwrites buf[(k-1)&3]: readers done >=1 barrier ago
    asm volatile("s_waitcnt vmcnt(9)" ::: "memory");
    __builtin_amdgcn_s_barrier();        // step-k loads visible to all waves
    COMPUTE(k & 3);
    __builtin_amdgcn_s_barrier();        // all waves done reading buf[k&3]
  }
  // ---- drain tail: steps KSTEPS-3 .. KSTEPS-1 ----
  asm volatile("s_waitcnt vmcnt(6)" ::: "memory");
  __builtin_amdgcn_s_barrier();
  COMPUTE((KSTEPS - 3) & 3);
  __builtin_amdgcn_s_barrier();
  asm volatile("s_waitcnt vmcnt(3)" ::: "memory");
  __builtin_amdgcn_s_barrier();
  COMPUTE((KSTEPS - 2) & 3);
  __builtin_amdgcn_s_barrier();
  asm volatile("s_waitcnt vmcnt(0)" ::: "memory");
  __builtin_amdgcn_s_barrier();
  COMPUTE((KSTEPS - 1) & 3);

  // ---------------- epilogue ----------------
#pragma unroll
  for (int mi = 0; mi < 2; ++mi) {
#pragma unroll
    for (int reg = 0; reg < 4; ++reg) {
      int p = blkPx + pxBase + mi * 16 + laneQ * 4 + reg;
      int bimg = p / 784;
      int hw = p % 784;
      size_t nchw = (size_t)bimg * 200704 + hw;
#pragma unroll
      for (int ni = 0; ni < 4; ++ni) {
        int o = blkCh + chBase + ni * 16 + lane16;
        float v = acc[mi][ni][reg] * al[ni] + bt[ni];
        if (MODE == 0) {
          v += x[nchw + (size_t)o * 784];             // residual x (f32)
          float t1 = v + pA[ni];
          t1 = (t1 > 0.f) ? t1 : pS[ni] * t1;         // PReLU
          float o1 = t1 + pB[ni];
          out1b[(size_t)p * 256 + o] = f2b(o1);
          act2[(size_t)p * 256 + o] = f2b(sgnf(o1 + p21[ni]));
        } else {
          v += b2f(out1b[(size_t)p * 256 + o]);       // residual out1 (bf16)
          float t1 = v + pA[ni];
          t1 = (t1 > 0.f) ? t1 : pS[ni] * t1;
          float o2 = t1 + pB[ni];
          dout[nchw + (size_t)o * 784] = o2;          // NCHW f32
        }
      }
    }
  }
}

// ---------------- launcher ----------------
extern "C" void kernel_launch(void* const* d_in, const int* in_sizes, int n_in,
                              void* d_out, int out_size, void* d_ws, size_t ws_size,
                              hipStream_t stream) {
  const float* x    = (const float*)d_in[0];
  const float* loss = (const float*)d_in[1];
  const float* b11  = (const float*)d_in[2];
  const float* b12  = (const float*)d_in[3];
  const float* b13  = (const float*)d_in[4];
  const float* b21  = (const float*)d_in[5];
  const float* b22  = (const float*)d_in[6];
  const float* b23  = (const float*)d_in[7];
  const float* w1   = (const float*)d_in[8];
  const float* w2   = (const float*)d_in[9];
  const float* g1   = (const float*)d_in[10];
  const float* be1  = (const float*)d_in[11];
  const float* m1   = (const float*)d_in[12];
  const float* v1   = (const float*)d_in[13];
  const float* g2   = (const float*)d_in[14];
  const float* be2  = (const float*)d_in[15];
  const float* m2   = (const float*)d_in[16];
  const float* v2   = (const float*)d_in[17];
  const float* a1   = (const float*)d_in[18];
  const float* a2   = (const float*)d_in[19];

  char* ws = (char*)d_ws;
  u16*   act1  = (u16*)(ws + 0ull);          // bf16 [25088][256] = 12,845,056 B
  u16*   act2  = (u16*)(ws + 12845056ull);   // bf16 [25088][256]
  u16*   out1b = (u16*)(ws + 25690112ull);   // bf16 [25088][256]
  u16*   wsgn1 = (u16*)(ws + 38535168ull);   // bf16 [256][2304]
  u16*   wsgn2 = (u16*)(ws + 39714816ull);   // bf16 [256][256]
  float* ab    = (float*)(ws + 39845888ull); // alpha1,beta1,alpha2,beta2 [4][256] f32
  float* zp    = (float*)(ws + 39849984ull); // 256 B zeros

  float* out = (float*)d_out;

  prep_kernel<<<512, 256, 0, stream>>>(w1, w2, g1, be1, m1, v1, g2, be2, m2, v2,
                                       wsgn1, wsgn2, ab, zp, out + (out_size - 1), loss);
  act1_kernel<<<dim3(7, 4, 32), 256, 0, stream>>>(x, b11, act1);
  gemm_kernel<0><<<dim3(392, 2), 256, 0, stream>>>(act1, wsgn1, ab, ab + 256,
      b12, a1, b13, b21, x, out1b, act2, (float*)nullptr, zp);
  gemm_kernel<1><<<dim3(392, 2), 256, 0, stream>>>(act2, wsgn2, ab + 512, ab + 768,
      b22, a2, b23, (const float*)nullptr, (const float*)nullptr, out1b, (u16*)nullptr, out, zp);
}

// Round 5
// 69.996 us; speedup vs baseline: 2.0175x; 2.0175x over previous
//
#include <hip/hip_runtime.h>
#include <hip/hip_bf16.h>

// BasicBlock (ReActNet) fused pipeline, MI355X gfx950.  R5 structural rewrite:
// fp8 e4m3 exact-sign GEMMs (A,B in {-1,0,+1} -> 0x38/0xB8/0x00), padded act1
// (32x30x30x256, zero borders), A-window resident in LDS (staged once/block),
// B streamed with 2-phase counted-vmcnt pipeline. Block = 112px x 128outch.

typedef unsigned short u16;
typedef unsigned char  u8;
typedef float f32x4 __attribute__((ext_vector_type(4)));

#define GLD16(gsrc, ldst) \
  __builtin_amdgcn_global_load_lds((__attribute__((address_space(1))) void*)(gsrc), \
                                   (__attribute__((address_space(3))) void*)(ldst), 16, 0, 0)

__device__ __forceinline__ float b2f(u16 u) {
  union { unsigned int i; float f; } c; c.i = ((unsigned int)u) << 16; return c.f;
}
__device__ __forceinline__ u16 f2b(float f) {
  unsigned int u = __builtin_bit_cast(unsigned int, f);
  unsigned int r = (u + 0x7FFFu + ((u >> 16) & 1u)) >> 16;   // RNE
  return (u16)r;
}
__device__ __forceinline__ u8 f2sign8(float v) {   // fp8 e4m3 of sign(v)
  return (v > 0.f) ? 0x38 : ((v < 0.f) ? 0xB8 : 0x00);
}

// ---------------- prep: fp8 sign weights (transposed [o][tap*256+ci]), fold scale*BN, loss ----
__global__ __launch_bounds__(256) void prep_kernel(
    const float* __restrict__ w1, const float* __restrict__ w2,
    const float* __restrict__ g1, const float* __restrict__ be1,
    const float* __restrict__ m1, const float* __restrict__ v1,
    const float* __restrict__ g2, const float* __restrict__ be2,
    const float* __restrict__ m2, const float* __restrict__ v2,
    u8* __restrict__ wsgn1, u8* __restrict__ wsgn2,
    float* __restrict__ ab,
    float* __restrict__ lossdst, const float* __restrict__ lossin)
{
  __shared__ float red[256];
  const int t = threadIdx.x;
  const int blk = blockIdx.x;
  float s = 0.f;
  if (blk < 256) {                       // w1: [o][ci][3x3] -> wsgn1[o][tap*256 + ci]
    const int o = blk;
    for (int jj = t; jj < 2304; jj += 256) {
      float v = w1[o * 2304 + jj];
      s += fabsf(v);
      int ci = jj / 9, tap = jj % 9;
      wsgn1[o * 2304 + tap * 256 + ci] = f2sign8(v);
    }
  } else {                               // w2: [o][ci] -> wsgn2[o][ci]
    const int o = blk - 256;
    float v = w2[o * 256 + t];
    s = fabsf(v);
    wsgn2[o * 256 + t] = f2sign8(v);
  }
  red[t] = s;
  __syncthreads();
  for (int st = 128; st > 0; st >>= 1) { if (t < st) red[t] += red[t + st]; __syncthreads(); }
  if (t == 0) {
    if (blk < 256) {
      const int o = blk;
      float scale = red[0] / 2304.f;
      float inv = g1[o] / sqrtf(v1[o] + 1e-5f);
      ab[o]       = scale * inv;                 // alpha1
      ab[256 + o] = be1[o] - m1[o] * inv;        // beta1
    } else {
      const int o = blk - 256;
      float scale = red[0] / 256.f;
      float inv = g2[o] / sqrtf(v2[o] + 1e-5f);
      ab[512 + o] = scale * inv;                 // alpha2
      ab[768 + o] = be2[o] - m2[o] * inv;        // beta2
    }
  }
  if (blk == 0 && t == 0) lossdst[0] = lossin[0];
}

// ------- act1 = fp8sign(x + b11), NCHW f32 -> PADDED (b,30,30,256) fp8; zero borders -------
__global__ __launch_bounds__(256) void act1_kernel(
    const float* __restrict__ x, const float* __restrict__ b11, u8* __restrict__ act1pad)
{
  __shared__ u8 lds8[112 * 64];
  const int t = threadIdx.x;
  const int pxgrp = blockIdx.x;        // 7 groups of 112 px (4 rows)
  const int c0 = blockIdx.y * 64;      // 4 ch groups
  const int img = blockIdx.z;
  const int p0 = pxgrp * 112;
  const float* xb = x + (size_t)img * 200704;
#pragma unroll
  for (int it = 0; it < 7; ++it) {     // read x coalesced, sign->fp8, LDS[p][c]
    int flat = it * 256 + t;           // c:64 x p4:28
    int c = flat / 28;
    int p = (flat % 28) * 4;
    float4 v4 = *(const float4*)(xb + (size_t)(c0 + c) * 784 + p0 + p);
    float bb = b11[c0 + c];
    lds8[(p + 0) * 64 + c] = f2sign8(v4.x + bb);
    lds8[(p + 1) * 64 + c] = f2sign8(v4.y + bb);
    lds8[(p + 2) * 64 + c] = f2sign8(v4.z + bb);
    lds8[(p + 3) * 64 + c] = f2sign8(v4.w + bb);
  }
  __syncthreads();
#pragma unroll
  for (int it = 0; it < 7; ++it) {     // write padded NHWC (4B per thread)
    int flat = it * 256 + t;           // px:112 x c4:16
    int px = flat >> 4;
    int c4 = (flat & 15) * 4;
    unsigned int v = *(const unsigned int*)(lds8 + px * 64 + c4);
    int pr = (px * 293) >> 13;         // px/28
    int pc = px - 28 * pr;
    size_t dst = ((size_t)img * 900 + (size_t)(pxgrp * 4 + 1 + pr) * 30 + 1 + pc) * 256 + c0 + c4;
    *(unsigned int*)(act1pad + dst) = v;
  }
  if (pxgrp == 0 && blockIdx.y == 0) { // zero this image's border (116 px x 256B)
    for (int idx = t; idx < 116 * 64; idx += 256) {
      int bp = idx >> 6;
      int l4 = (idx & 63) * 4;
      int br, bc;
      if (bp < 30)      { br = 0;       bc = bp; }
      else if (bp < 60) { br = 29;      bc = bp - 30; }
      else if (bp < 88) { br = bp - 59; bc = 0; }
      else              { br = bp - 87; bc = 29; }
      *(unsigned int*)(act1pad + ((size_t)img * 900 + br * 30 + bc) * 256 + l4) = 0u;
    }
  }
}

// ---------------- GEMM (MODE 0: conv3x3 K=2304 pad ; MODE 1: conv1x1 K=256) ----------------
// Block = 112 px (4 image rows) x 128 out-ch, 4 waves (each 112px x 32ch).
// A-window resident in LDS (staged once, XOR-swizzled via pre-swizzled source).
// B streamed in BK=128 chunks, double-buffered, counted vmcnt(4).
template<int MODE>
__global__ __launch_bounds__(256, 2) void gemm_kernel(
    const u8* __restrict__ aglob,      // MODE0: act1pad ; MODE1: act2f8
    const u8* __restrict__ wsgn,       // fp8 [256][KB]
    const float* __restrict__ alphav,
    const float* __restrict__ betav,
    const float* __restrict__ biasA,   // b12 / b22
    const float* __restrict__ slope,   // a1  / a2
    const float* __restrict__ biasB,   // b13 / b23
    const float* __restrict__ b21,     // MODE0 only
    const float* __restrict__ x,       // MODE0 only: NCHW f32 residual
    u16* __restrict__ out1b,           // MODE0: write bf16 NHWC ; MODE1: read
    u8* __restrict__ act2,             // MODE0: write fp8 signs NHWC
    float* __restrict__ dout)          // MODE1: write NCHW f32
{
  constexpr int KB     = (MODE == 0) ? 2304 : 256;     // bytes per wsgn row
  constexpr int KSTEPS = (MODE == 0) ? 18 : 2;         // BK=128
  constexpr int WINB   = (MODE == 0) ? 46080 : 28672;  // 6*30*256 | 112*256
  constexpr int WCHUNK = WINB / 16;

  __shared__ __align__(16) u8 winlds[WINB];
  __shared__ __align__(16) u8 ldsB[2][16384];          // 128 rows x 128B

  const int t = threadIdx.x;
  const int w = t >> 6;
  const int l = t & 63;
  const int lane16 = l & 15;
  const int lq  = l >> 4;
  const int lq8 = lq * 8;
  const int pxblk = blockIdx.x;        // 224
  const int chblk = blockIdx.y;        // 2
  const int img = pxblk / 7;
  const int rowgrp = pxblk % 7;

  const u8* winsrc = (MODE == 0)
      ? aglob + ((size_t)img * 900 + (size_t)rowgrp * 4 * 30) * 256
      : aglob + (size_t)pxblk * 112 * 256;

  // per-lane pixel bases for the 7 m-tiles
  int basepix[7];
#pragma unroll
  for (int m = 0; m < 7; ++m) {
    int pm = m * 16 + lane16;
    if (MODE == 0) {
      int r = (pm * 293) >> 13;        // pm/28
      basepix[m] = r * 30 + (pm - 28 * r);
    } else {
      basepix[m] = pm;
    }
  }
  const int obyte0 = (w * 32 + lane16) * 128;
  const int obyte1 = obyte0 + 2048;
  const int x7b = (lane16 & 7) << 4;

  f32x4 acc[7][2];
  f32x4 zero4 = {0.f, 0.f, 0.f, 0.f};
#pragma unroll
  for (int m = 0; m < 7; ++m) { acc[m][0] = zero4; acc[m][1] = zero4; }

  char* wl = (char*)winlds;
  char* bB = (char*)&ldsB[0][0];
  const char* wsc = (const char*)wsgn;

  auto STAGE_B = [&](int buf, int s) {   // 4 GLD16/thread, uniform
#pragma unroll
    for (int i = 0; i < 4; ++i) {
      int c = i * 256 + t;
      int o = c >> 3;
      int inner = ((c & 7) * 16) ^ ((o & 7) << 4);
      const char* src = wsc + (size_t)(chblk * 128 + o) * KB + s * 128 + inner;
      GLD16(src, bB + buf * 16384 + c * 16);
    }
  };

  auto COMPUTE = [&](int buf, int s) {
    int tap, ci0;
    if (MODE == 0) { tap = s >> 1; ci0 = (s & 1) << 7; }
    else           { tap = 0;      ci0 = s << 7; }
    int ti = (tap * 11) >> 5;            // tap/3
    int tapoff = ti * 30 + (tap - 3 * ti);
    int pb[7], x7[7];
#pragma unroll
    for (int m = 0; m < 7; ++m) {
      int wp = basepix[m] + tapoff;
      pb[m] = wp << 8;
      x7[m] = (wp & 7) << 4;
    }
    const char* sB = bB + buf * 16384;
#pragma unroll
    for (int sl = 0; sl < 4; ++sl) {
      int kin = ci0 + sl * 32 + lq8;     // A inner (256B pixel row)
      int kb  = sl * 32 + lq8;           // B inner (128B chunk row)
      long bv0 = *(const long*)(sB + obyte0 + (kb ^ x7b));
      long bv1 = *(const long*)(sB + obyte1 + (kb ^ x7b));
      long av[7];
#pragma unroll
      for (int m = 0; m < 7; ++m)
        av[m] = *(const long*)(wl + pb[m] + (kin ^ x7[m]));
#pragma unroll
      for (int m = 0; m < 7; ++m) {
        acc[m][0] = __builtin_amdgcn_mfma_f32_16x16x32_fp8_fp8(av[m], bv0, acc[m][0], 0, 0, 0);
        acc[m][1] = __builtin_amdgcn_mfma_f32_16x16x32_fp8_fp8(av[m], bv1, acc[m][1], 0, 0, 0);
      }
    }
  };

  // ---- prologue: stage A-window (once) + B(0); drain; barrier ----
#pragma unroll
  for (int i = 0; i < WCHUNK / 256; ++i) {
    int c = i * 256 + t;
    int pix = c >> 4;
    int inner = ((c & 15) * 16) ^ ((pix & 7) << 4);
    GLD16(winsrc + pix * 256 + inner, wl + c * 16);
  }
  if ((WCHUNK & 255) != 0) {             // MODE0 tail: 64 chunks (wave 0)
    int c = (WCHUNK / 256) * 256 + t;
    if (c < WCHUNK) {
      int pix = c >> 4;
      int inner = ((c & 15) * 16) ^ ((pix & 7) << 4);
      GLD16(winsrc + pix * 256 + inner, wl + c * 16);
    }
  }
  STAGE_B(0, 0);
  asm volatile("s_waitcnt vmcnt(0)" ::: "memory");
  __builtin_amdgcn_s_barrier();

  // ---- main loop: 2-phase counted pipeline ----
#pragma unroll 1
  for (int s = 0; s < KSTEPS - 1; ++s) {
    STAGE_B((s + 1) & 1, s + 1);
    asm volatile("s_waitcnt vmcnt(4)" ::: "memory");   // B(s) landed; B(s+1) in flight
    __builtin_amdgcn_s_barrier();
    __builtin_amdgcn_s_setprio(1);
    COMPUTE(s & 1, s);
    __builtin_amdgcn_s_setprio(0);
    __builtin_amdgcn_s_barrier();
  }
  asm volatile("s_waitcnt vmcnt(0)" ::: "memory");
  __builtin_amdgcn_s_barrier();
  COMPUTE((KSTEPS - 1) & 1, KSTEPS - 1);

  // ---------------- epilogue ----------------
  const int O0 = chblk * 128 + w * 32 + lane16;
  float al[2], bt[2], pA_[2], pS[2], pB_[2], p21[2];
#pragma unroll
  for (int n = 0; n < 2; ++n) {
    int O = O0 + n * 16;
    al[n] = alphav[O]; bt[n] = betav[O];
    pA_[n] = biasA[O]; pS[n] = slope[O]; pB_[n] = biasB[O];
    p21[n] = (MODE == 0) ? b21[O] : 0.f;
  }
  const int hwb = rowgrp * 112 + lq * 4;
#pragma unroll
  for (int m = 0; m < 7; ++m) {
    int hwm = hwb + m * 16;
    int gp = img * 784 + hwm;            // global pixel (+reg)
#pragma unroll
    for (int n = 0; n < 2; ++n) {
      int O = O0 + n * 16;
      if (MODE == 0) {
        float4 xr = *(const float4*)(x + ((size_t)(img * 256 + O) * 784 + hwm));
        float xv[4] = {xr.x, xr.y, xr.z, xr.w};
#pragma unroll
        for (int reg = 0; reg < 4; ++reg) {
          float v = acc[m][n][reg] * al[n] + bt[n] + xv[reg];
          float t1 = v + pA_[n];
          t1 = (t1 > 0.f) ? t1 : pS[n] * t1;
          float o1 = t1 + pB_[n];
          size_t idx = (size_t)(gp + reg) * 256 + O;
          out1b[idx] = f2b(o1);
          act2[idx] = f2sign8(o1 + p21[n]);
        }
      } else {
        float rv[4];
#pragma unroll
        for (int reg = 0; reg < 4; ++reg) {
          size_t idx = (size_t)(gp + reg) * 256 + O;
          float v = acc[m][n][reg] * al[n] + bt[n] + b2f(out1b[idx]);
          float t1 = v + pA_[n];
          t1 = (t1 > 0.f) ? t1 : pS[n] * t1;
          rv[reg] = t1 + pB_[n];
        }
        float4 r4 = {rv[0], rv[1], rv[2], rv[3]};
        *(float4*)(dout + ((size_t)(img * 256 + O) * 784 + hwm)) = r4;
      }
    }
  }
}

// ---------------- launcher ----------------
extern "C" void kernel_launch(void* const* d_in, const int* in_sizes, int n_in,
                              void* d_out, int out_size, void* d_ws, size_t ws_size,
                              hipStream_t stream) {
  const float* x    = (const float*)d_in[0];
  const float* loss = (const float*)d_in[1];
  const float* b11  = (const float*)d_in[2];
  const float* b12  = (const float*)d_in[3];
  const float* b13  = (const float*)d_in[4];
  const float* b21  = (const float*)d_in[5];
  const float* b22  = (const float*)d_in[6];
  const float* b23  = (const float*)d_in[7];
  const float* w1   = (const float*)d_in[8];
  const float* w2   = (const float*)d_in[9];
  const float* g1   = (const float*)d_in[10];
  const float* be1  = (const float*)d_in[11];
  const float* m1   = (const float*)d_in[12];
  const float* v1   = (const float*)d_in[13];
  const float* g2   = (const float*)d_in[14];
  const float* be2  = (const float*)d_in[15];
  const float* m2   = (const float*)d_in[16];
  const float* v2   = (const float*)d_in[17];
  const float* a1   = (const float*)d_in[18];
  const float* a2   = (const float*)d_in[19];

  char* ws = (char*)d_ws;
  u8*    act1pad = (u8*)(ws + 0ull);           // fp8 (32,30,30,256) = 7,372,800
  u8*    act2f8  = (u8*)(ws + 7372800ull);     // fp8 (25088,256)    = 6,422,528
  u16*   out1b   = (u16*)(ws + 13795328ull);   // bf16 (25088,256)   = 12,845,056
  u8*    wsgn1f8 = (u8*)(ws + 26640384ull);    // fp8 (256,2304)
  u8*    wsgn2f8 = (u8*)(ws + 27230208ull);    // fp8 (256,256)
  float* ab      = (float*)(ws + 27295744ull); // 4 x 256 f32

  float* out = (float*)d_out;

  prep_kernel<<<512, 256, 0, stream>>>(w1, w2, g1, be1, m1, v1, g2, be2, m2, v2,
                                       wsgn1f8, wsgn2f8, ab, out + (out_size - 1), loss);
  act1_kernel<<<dim3(7, 4, 32), 256, 0, stream>>>(x, b11, act1pad);
  gemm_kernel<0><<<dim3(224, 2), 256, 0, stream>>>(act1pad, wsgn1f8, ab, ab + 256,
      b12, a1, b13, b21, x, out1b, act2f8, (float*)nullptr);
  gemm_kernel<1><<<dim3(224, 2), 256, 0, stream>>>(act2f8, wsgn2f8, ab + 512, ab + 768,
      b22, a2, b23, (const float*)nullptr, (const float*)nullptr, out1b, (u8*)nullptr, out);
}